// Round 1
// baseline (537.138 us; speedup 1.0000x reference)
//
#include <hip/hip_runtime.h>

typedef unsigned short u16;
typedef __bf16 bf16x8 __attribute__((ext_vector_type(8)));
typedef float f32x4 __attribute__((ext_vector_type(4)));

typedef __attribute__((address_space(1))) const void* as1_cvp;
typedef __attribute__((address_space(3))) void* as3_vp;

// ---------- bf16 helpers ----------
__device__ __forceinline__ float b2f(u16 u) {
  union { unsigned int i; float f; } x; x.i = ((unsigned int)u) << 16; return x.f;
}
__device__ __forceinline__ u16 f2b(float f) {
  union { float f; unsigned int i; } x; x.f = f;
  unsigned int u = x.i;
  u += 0x7fffu + ((u >> 16) & 1u);   // round-to-nearest-even
  return (u16)(u >> 16);
}

// ---------- dtype detector: flag=1 if inputs are fp32, 0 if bf16 ----------
// bf16 data: every ushort is a sane bf16 (exp field ~[100,150] or zero).
// fp32 data: low halves of floats have ~uniform random exp field (~60% sane overall).
__global__ void k_detect(const u16* __restrict__ x, int* __restrict__ flag) {
  int t = threadIdx.x;
  int sane = 0;
#pragma unroll
  for (int i = 0; i < 8; ++i) {
    u16 u = x[t * 8 + i];
    int e = (u >> 7) & 0xFF;
    sane += (u == 0 || (e >= 100 && e <= 150)) ? 1 : 0;
  }
#pragma unroll
  for (int off = 32; off >= 1; off >>= 1) sane += __shfl_xor(sane, off);
  if (t == 0) *flag = (sane < 480) ? 1 : 0;
}

// ---------- x -> bf16 (copy or downconvert), 4 elems/thread ----------
__global__ void k_convert(const void* __restrict__ xin, u16* __restrict__ xb,
                          const int* __restrict__ flagp) {
  long i = ((long)blockIdx.x * 256 + threadIdx.x) * 4;
  if (*flagp) {
    float4 v = *(const float4*)((const float*)xin + i);
    u16* o = xb + i;
    o[0] = f2b(v.x); o[1] = f2b(v.y); o[2] = f2b(v.z); o[3] = f2b(v.w);
  } else {
    *(ushort4*)(xb + i) = *(const ushort4*)((const u16*)xin + i);
  }
}

// ---------- W[K][N] -> WT[N][K] as bf16 ----------
__global__ void k_transpose(const void* __restrict__ W, u16* __restrict__ WT,
                            const int* __restrict__ flagp, int K, int N) {
  __shared__ u16 tile[32][33];
  int f = *flagp;
  int n0 = blockIdx.x * 32, k0 = blockIdx.y * 32;
  int tx = threadIdx.x, ty = threadIdx.y;
#pragma unroll
  for (int i = 0; i < 32; i += 8) {
    long idx = (long)(k0 + ty + i) * N + n0 + tx;
    tile[ty + i][tx] = f ? f2b(((const float*)W)[idx]) : ((const u16*)W)[idx];
  }
  __syncthreads();
#pragma unroll
  for (int i = 0; i < 32; i += 8)
    WT[(long)(n0 + ty + i) * K + k0 + tx] = tile[tx][ty + i];
}

// ---------- biasM[h][i][j] = table[rel[i][j]][h], fp32 ----------
__global__ void k_bias(const int* __restrict__ rel, const void* __restrict__ table,
                       float* __restrict__ biasM, const int* __restrict__ flagp) {
  int idx = blockIdx.x * 256 + threadIdx.x;
  if (idx >= 16 * 98 * 98) return;
  int f = *flagp;
  int j = idx % 98, i = (idx / 98) % 98, h = idx / (98 * 98);
  int r = rel[i * 98 + j];
  biasM[idx] = f ? ((const float*)table)[r * 16 + h] : b2f(((const u16*)table)[r * 16 + h]);
}

// ---------- m97-style bf16 GEMM: C[M][N] = A[M][K] * BT[N][K]^T + bias ----------
// 128x128 tile, BK=32, 256 thr / 4 waves (2x2), global_load_lds width-16 staging.
__global__ __launch_bounds__(256) void k_gemm_bt(
    const u16* __restrict__ A, const u16* __restrict__ BT,
    const void* __restrict__ bias, void* __restrict__ C,
    const int* __restrict__ flagp, int N, int K, int out_follows_flag) {
  __shared__ __align__(16) u16 As[128 * 32];
  __shared__ __align__(16) u16 Bs[128 * 32];
  const int t = threadIdx.x, w = t >> 6, ln = t & 63;
  const long bm = (long)blockIdx.x * 128, bn = (long)blockIdx.y * 128;
  const int lrow = ln >> 2, lseg = ln & 3;
  // staging: each wave stages 32 rows of A and B (2 instrs each, 16 rows/instr)
  const u16* ag0 = A + (bm + w * 32 + lrow) * (long)K + lseg * 8;
  const u16* ag1 = ag0 + 16L * K;
  const u16* bg0 = BT + (bn + w * 32 + lrow) * (long)K + lseg * 8;
  const u16* bg1 = bg0 + 16L * K;
  u16* As0 = &As[w * 1024]; u16* As1 = &As[w * 1024 + 512];
  u16* Bs0 = &Bs[w * 1024]; u16* Bs1 = &Bs[w * 1024 + 512];
  const int wm = w & 1, wn = w >> 1;
  const int col = ln & 15, qrow = ln >> 4;
  f32x4 acc[4][4] = {};
  for (int k0 = 0; k0 < K; k0 += 32) {
    __syncthreads();  // previous iter's LDS reads done
    __builtin_amdgcn_global_load_lds((as1_cvp)(const void*)(ag0 + k0), (as3_vp)As0, 16, 0, 0);
    __builtin_amdgcn_global_load_lds((as1_cvp)(const void*)(ag1 + k0), (as3_vp)As1, 16, 0, 0);
    __builtin_amdgcn_global_load_lds((as1_cvp)(const void*)(bg0 + k0), (as3_vp)Bs0, 16, 0, 0);
    __builtin_amdgcn_global_load_lds((as1_cvp)(const void*)(bg1 + k0), (as3_vp)Bs1, 16, 0, 0);
    __syncthreads();  // drains vmcnt: staged data visible
    bf16x8 af[4], bfr[4];
#pragma unroll
    for (int mi = 0; mi < 4; ++mi)
      af[mi] = *(const bf16x8*)&As[(wm * 64 + mi * 16 + col) * 32 + qrow * 8];
#pragma unroll
    for (int ni = 0; ni < 4; ++ni)
      bfr[ni] = *(const bf16x8*)&Bs[(wn * 64 + ni * 16 + col) * 32 + qrow * 8];
#pragma unroll
    for (int mi = 0; mi < 4; ++mi)
#pragma unroll
      for (int ni = 0; ni < 4; ++ni)
        acc[mi][ni] = __builtin_amdgcn_mfma_f32_16x16x32_bf16(af[mi], bfr[ni], acc[mi][ni], 0, 0, 0);
  }
  const int f = *flagp;
  const int of = out_follows_flag ? f : 0;
  float bv[4];
#pragma unroll
  for (int ni = 0; ni < 4; ++ni) {
    long c = bn + wn * 64 + ni * 16 + col;
    bv[ni] = f ? ((const float*)bias)[c] : b2f(((const u16*)bias)[c]);
  }
#pragma unroll
  for (int mi = 0; mi < 4; ++mi)
#pragma unroll
    for (int ni = 0; ni < 4; ++ni)
#pragma unroll
      for (int r = 0; r < 4; ++r) {
        long row = bm + wm * 64 + mi * 16 + qrow * 4 + r;
        long c = bn + wn * 64 + ni * 16 + col;
        float v = acc[mi][ni][r] + bv[ni];
        if (of) ((float*)C)[row * N + c] = v;
        else    ((u16*)C)[row * N + c] = f2b(v);
      }
}

// ---------- fused window attention: one block per (b,h), 4 waves ----------
// LDS: Q[112][32], K[128][32] (zero-padded), Vt[32][136], P[112][136] (all bf16).
// Wave w owns i-tiles {w, w+4}; QK^T (8 mfma) -> reg softmax -> P via LDS -> PV (8 mfma).
__global__ __launch_bounds__(256) void k_attn(
    const u16* __restrict__ qkv, const float* __restrict__ biasM, u16* __restrict__ attnout) {
  __shared__ __align__(16) u16 Qs[112 * 32];
  __shared__ __align__(16) u16 Ks[128 * 32];
  __shared__ __align__(16) u16 Vt[32 * 136];
  __shared__ __align__(16) u16 Ps[112 * 136];
  const int b = blockIdx.x, h = blockIdx.y;
  const int t = threadIdx.x;
  {  // zero pads (whole arrays, cheap)
    unsigned int* z = (unsigned int*)Qs;
    for (int i = t; i < 1792; i += 256) z[i] = 0;
    z = (unsigned int*)Ks;
    for (int i = t; i < 2048; i += 256) z[i] = 0;
    z = (unsigned int*)Vt;
    for (int i = t; i < 2176; i += 256) z[i] = 0;
  }
  __syncthreads();
  {  // stage Q,K row-major; V transposed
    const int r0 = t >> 3, c4 = (t & 7) * 4;
    const u16* base = qkv + ((long)b * 98) * 1536 + h * 32;
#pragma unroll
    for (int it = 0; it < 4; ++it) {
      int r = r0 + it * 32;
      if (r < 98) {
        const u16* rowp = base + (long)r * 1536;
        *(ushort4*)&Qs[r * 32 + c4] = *(const ushort4*)(rowp + c4);
        *(ushort4*)&Ks[r * 32 + c4] = *(const ushort4*)(rowp + 512 + c4);
        ushort4 v4 = *(const ushort4*)(rowp + 1024 + c4);
        Vt[(c4 + 0) * 136 + r] = v4.x;
        Vt[(c4 + 1) * 136 + r] = v4.y;
        Vt[(c4 + 2) * 136 + r] = v4.z;
        Vt[(c4 + 3) * 136 + r] = v4.w;
      }
    }
  }
  __syncthreads();
  const int w = t >> 6, ln = t & 63;
  const int col = ln & 15, qrow = ln >> 4;
  const float scale = 0.17677669529663687f;  // 32^-0.5
  const float* bh = biasM + h * (98 * 98);
  for (int tt = 0; tt < 2; ++tt) {
    const int ti = w + tt * 4;
    if (ti >= 7) break;
    bf16x8 aq = *(const bf16x8*)&Qs[(ti * 16 + col) * 32 + qrow * 8];
    f32x4 s[8];
#pragma unroll
    for (int tj = 0; tj < 8; ++tj) {
      bf16x8 bk = *(const bf16x8*)&Ks[(tj * 16 + col) * 32 + qrow * 8];
      f32x4 z = {0.f, 0.f, 0.f, 0.f};
      s[tj] = __builtin_amdgcn_mfma_f32_16x16x32_bf16(aq, bk, z, 0, 0, 0);
    }
    // bias + mask + softmax per row (C layout: row = qrow*4+r, col = lane&15)
#pragma unroll
    for (int r = 0; r < 4; ++r) {
      const int i = ti * 16 + qrow * 4 + r;
      const int ib = (i < 98) ? i : 97;  // clamp bias read for pad rows (discarded later)
      float vals[8];
      float m = -1e30f;
#pragma unroll
      for (int tj = 0; tj < 8; ++tj) {
        int j = tj * 16 + col;
        float v = (j < 98) ? (s[tj][r] * scale + bh[ib * 98 + j]) : -1e30f;
        vals[tj] = v;
        m = fmaxf(m, v);
      }
#pragma unroll
      for (int off = 1; off < 16; off <<= 1) m = fmaxf(m, __shfl_xor(m, off));
      float sum = 0.f;
#pragma unroll
      for (int tj = 0; tj < 8; ++tj) { vals[tj] = __expf(vals[tj] - m); sum += vals[tj]; }
#pragma unroll
      for (int off = 1; off < 16; off <<= 1) sum += __shfl_xor(sum, off);
      float inv = 1.f / sum;
#pragma unroll
      for (int tj = 0; tj < 8; ++tj)
        Ps[i * 136 + tj * 16 + col] = f2b(vals[tj] * inv);
    }
    // PV: out[i][d] = sum_j P[i][j] V[j][d]; wave reads only rows it wrote
    f32x4 o0 = {0.f, 0.f, 0.f, 0.f}, o1 = {0.f, 0.f, 0.f, 0.f};
#pragma unroll
    for (int ks = 0; ks < 4; ++ks) {
      bf16x8 ap  = *(const bf16x8*)&Ps[(ti * 16 + col) * 136 + ks * 32 + qrow * 8];
      bf16x8 bv0 = *(const bf16x8*)&Vt[col * 136 + ks * 32 + qrow * 8];
      bf16x8 bv1 = *(const bf16x8*)&Vt[(16 + col) * 136 + ks * 32 + qrow * 8];
      o0 = __builtin_amdgcn_mfma_f32_16x16x32_bf16(ap, bv0, o0, 0, 0, 0);
      o1 = __builtin_amdgcn_mfma_f32_16x16x32_bf16(ap, bv1, o1, 0, 0, 0);
    }
#pragma unroll
    for (int r = 0; r < 4; ++r) {
      const int i = ti * 16 + qrow * 4 + r;
      if (i < 98) {
        u16* op = attnout + ((long)(b * 98 + i)) * 512 + h * 32;
        op[col] = f2b(o0[r]);
        op[16 + col] = f2b(o1[r]);
      }
    }
  }
}

extern "C" void kernel_launch(void* const* d_in, const int* in_sizes, int n_in,
                              void* d_out, int out_size, void* d_ws, size_t ws_size,
                              hipStream_t stream) {
  (void)in_sizes; (void)n_in; (void)out_size; (void)ws_size;
  // Workspace carve (~208.2 MB). xb aliases attnbuf (xb dead before attn writes).
  char* p = (char*)d_ws;
  u16* qkvbuf  = (u16*)p;  p += 50176L * 1536 * 2;   // 154,140,672
  u16* attnbuf = (u16*)p;  u16* xb = attnbuf; p += 50176L * 512 * 2;  // 51,380,224
  u16* wqkvT   = (u16*)p;  p += 1536L * 512 * 2;     // 1,572,864
  u16* wprojT  = (u16*)p;  p += 512L * 512 * 2;      // 524,288
  float* biasM = (float*)p; p += 16L * 98 * 98 * 4;  // 614,656
  int* flagp   = (int*)p;

  k_detect<<<1, 64, 0, stream>>>((const u16*)d_in[0], flagp);
  k_convert<<<25088, 256, 0, stream>>>(d_in[0], xb, flagp);  // 25,690,112 / 4 / 256
  k_transpose<<<dim3(48, 16), dim3(32, 8), 0, stream>>>(d_in[1], wqkvT, flagp, 512, 1536);
  k_transpose<<<dim3(16, 16), dim3(32, 8), 0, stream>>>(d_in[3], wprojT, flagp, 512, 512);
  k_bias<<<601, 256, 0, stream>>>((const int*)d_in[6], d_in[5], biasM, flagp);
  // qkv = x @ qkv_w + qkv_b   [50176 x 1536]
  k_gemm_bt<<<dim3(392, 12), 256, 0, stream>>>(xb, wqkvT, d_in[2], qkvbuf, flagp, 1536, 512, 0);
  // attention -> attnbuf [50176 x 512] (layout b, n, h*32+d)
  k_attn<<<dim3(512, 16), 256, 0, stream>>>(qkvbuf, biasM, attnbuf);
  // out = attnbuf @ proj_w + proj_b
  k_gemm_bt<<<dim3(392, 4), 256, 0, stream>>>(attnbuf, wprojT, d_in[4], d_out, flagp, 512, 512, 1);
}

// Round 2
// 464.799 us; speedup vs baseline: 1.1556x; 1.1556x over previous
//
#include <hip/hip_runtime.h>

typedef unsigned short u16;
typedef __bf16 bf16x8 __attribute__((ext_vector_type(8)));
typedef float f32x4 __attribute__((ext_vector_type(4)));

typedef __attribute__((address_space(1))) const void* as1_cvp;
typedef __attribute__((address_space(3))) void* as3_vp;

// ---------- bf16 helpers ----------
__device__ __forceinline__ float b2f(u16 u) {
  union { unsigned int i; float f; } x; x.i = ((unsigned int)u) << 16; return x.f;
}
__device__ __forceinline__ u16 f2b(float f) {
  union { float f; unsigned int i; } x; x.f = f;
  unsigned int u = x.i;
  u += 0x7fffu + ((u >> 16) & 1u);   // round-to-nearest-even
  return (u16)(u >> 16);
}

// ---------- dtype detector: flag=1 if inputs are fp32, 0 if bf16 ----------
__global__ void k_detect(const u16* __restrict__ x, int* __restrict__ flag) {
  int t = threadIdx.x;
  int sane = 0;
#pragma unroll
  for (int i = 0; i < 8; ++i) {
    u16 u = x[t * 8 + i];
    int e = (u >> 7) & 0xFF;
    sane += (u == 0 || (e >= 100 && e <= 150)) ? 1 : 0;
  }
#pragma unroll
  for (int off = 32; off >= 1; off >>= 1) sane += __shfl_xor(sane, off);
  if (t == 0) *flag = (sane < 480) ? 1 : 0;
}

// ---------- x -> bf16 downconvert; no-op when inputs already bf16 ----------
__global__ void k_convert(const void* __restrict__ xin, u16* __restrict__ xb,
                          const int* __restrict__ flagp) {
  if (!*flagp) return;  // bf16 inputs: GEMM1 reads raw input directly
  long i = ((long)blockIdx.x * 256 + threadIdx.x) * 4;
  float4 v = *(const float4*)((const float*)xin + i);
  u16* o = xb + i;
  o[0] = f2b(v.x); o[1] = f2b(v.y); o[2] = f2b(v.z); o[3] = f2b(v.w);
}

// ---------- W[K][N] -> WT[N][K] as bf16 ----------
__global__ void k_transpose(const void* __restrict__ W, u16* __restrict__ WT,
                            const int* __restrict__ flagp, int K, int N) {
  __shared__ u16 tile[32][33];
  int f = *flagp;
  int n0 = blockIdx.x * 32, k0 = blockIdx.y * 32;
  int tx = threadIdx.x, ty = threadIdx.y;
#pragma unroll
  for (int i = 0; i < 32; i += 8) {
    long idx = (long)(k0 + ty + i) * N + n0 + tx;
    tile[ty + i][tx] = f ? f2b(((const float*)W)[idx]) : ((const u16*)W)[idx];
  }
  __syncthreads();
#pragma unroll
  for (int i = 0; i < 32; i += 8)
    WT[(long)(n0 + ty + i) * K + k0 + tx] = tile[tx][ty + i];
}

// ---------- bias in MFMA C-fragment order, bf16, mask baked in ----------
// BiasFrag[h][ti(7)][tj(8)][lane(64)][r(4)]; value = bias[h][ti*16+qrow*4+r][tj*16+col]
// (i clamped to 97; j>=98 -> -1e30 so masking is free in-kernel).
__global__ void k_biasfrag(const int* __restrict__ rel, const void* __restrict__ table,
                           u16* __restrict__ biasFrag, const int* __restrict__ flagp) {
  int t = blockIdx.x * 256 + threadIdx.x;   // 57344 total
  int f = *flagp;
  int ln = t & 63, r2 = t >> 6;
  int tj = r2 & 7, r3 = r2 >> 3;
  int ti = r3 % 7, h = r3 / 7;
  int col = ln & 15, qrow = ln >> 4;
  int j = tj * 16 + col;
  u16 v[4];
#pragma unroll
  for (int r = 0; r < 4; ++r) {
    int i = ti * 16 + qrow * 4 + r; if (i > 97) i = 97;
    float val;
    if (j < 98) {
      int rr = rel[i * 98 + j];
      val = f ? ((const float*)table)[rr * 16 + h] : b2f(((const u16*)table)[rr * 16 + h]);
    } else {
      val = -1e30f;
    }
    v[r] = f2b(val);
  }
  ushort4 out; out.x = v[0]; out.y = v[1]; out.z = v[2]; out.w = v[3];
  *(ushort4*)(biasFrag + (long)t * 4) = out;
}

// ---------- m97-style bf16 GEMM: C[M][N] = A[M][K] * BT[N][K]^T + bias ----------
__global__ __launch_bounds__(256) void k_gemm_bt(
    const u16* __restrict__ A_raw, const u16* __restrict__ A_conv,
    const u16* __restrict__ BT, const void* __restrict__ bias, void* __restrict__ C,
    const int* __restrict__ flagp, int N, int K, int out_follows_flag) {
  __shared__ __align__(16) u16 As[128 * 32];
  __shared__ __align__(16) u16 Bs[128 * 32];
  const int f = *flagp;
  const u16* A = f ? A_conv : A_raw;
  const int t = threadIdx.x, w = t >> 6, ln = t & 63;
  const long bm = (long)blockIdx.x * 128, bn = (long)blockIdx.y * 128;
  const int lrow = ln >> 2, lseg = ln & 3;
  const u16* ag0 = A + (bm + w * 32 + lrow) * (long)K + lseg * 8;
  const u16* ag1 = ag0 + 16L * K;
  const u16* bg0 = BT + (bn + w * 32 + lrow) * (long)K + lseg * 8;
  const u16* bg1 = bg0 + 16L * K;
  u16* As0 = &As[w * 1024]; u16* As1 = &As[w * 1024 + 512];
  u16* Bs0 = &Bs[w * 1024]; u16* Bs1 = &Bs[w * 1024 + 512];
  const int wm = w & 1, wn = w >> 1;
  const int col = ln & 15, qrow = ln >> 4;
  f32x4 acc[4][4] = {};
  for (int k0 = 0; k0 < K; k0 += 32) {
    __syncthreads();
    __builtin_amdgcn_global_load_lds((as1_cvp)(const void*)(ag0 + k0), (as3_vp)As0, 16, 0, 0);
    __builtin_amdgcn_global_load_lds((as1_cvp)(const void*)(ag1 + k0), (as3_vp)As1, 16, 0, 0);
    __builtin_amdgcn_global_load_lds((as1_cvp)(const void*)(bg0 + k0), (as3_vp)Bs0, 16, 0, 0);
    __builtin_amdgcn_global_load_lds((as1_cvp)(const void*)(bg1 + k0), (as3_vp)Bs1, 16, 0, 0);
    __syncthreads();
    bf16x8 af[4], bfr[4];
#pragma unroll
    for (int mi = 0; mi < 4; ++mi)
      af[mi] = *(const bf16x8*)&As[(wm * 64 + mi * 16 + col) * 32 + qrow * 8];
#pragma unroll
    for (int ni = 0; ni < 4; ++ni)
      bfr[ni] = *(const bf16x8*)&Bs[(wn * 64 + ni * 16 + col) * 32 + qrow * 8];
#pragma unroll
    for (int mi = 0; mi < 4; ++mi)
#pragma unroll
      for (int ni = 0; ni < 4; ++ni)
        acc[mi][ni] = __builtin_amdgcn_mfma_f32_16x16x32_bf16(af[mi], bfr[ni], acc[mi][ni], 0, 0, 0);
  }
  const int of = out_follows_flag ? f : 0;
  float bv[4];
#pragma unroll
  for (int ni = 0; ni < 4; ++ni) {
    long c = bn + wn * 64 + ni * 16 + col;
    bv[ni] = f ? ((const float*)bias)[c] : b2f(((const u16*)bias)[c]);
  }
#pragma unroll
  for (int mi = 0; mi < 4; ++mi)
#pragma unroll
    for (int ni = 0; ni < 4; ++ni)
#pragma unroll
      for (int r = 0; r < 4; ++r) {
        long row = bm + wm * 64 + mi * 16 + qrow * 4 + r;
        long c = bn + wn * 64 + ni * 16 + col;
        float v = acc[mi][ni][r] + bv[ni];
        if (of) ((float*)C)[row * N + c] = v;
        else    ((u16*)C)[row * N + c] = f2b(v);
      }
}

// ---------- fused window attention v2: one block per (b,h), 4 waves ----------
// LDS 41.5KB -> 3 blocks/CU. Q/K staged via global_load_lds (row clamp, no zero-init).
// Bias from fragment-ordered table (coalesced 8B loads, mask baked in). Per-wave Ps
// slot. Output round-trips through LDS (aliases Qs) for coalesced ushort4 stores.
__global__ __launch_bounds__(256) void k_attn(
    const u16* __restrict__ qkv, const u16* __restrict__ biasFrag,
    u16* __restrict__ attnout) {
  __shared__ __align__(16) u16 Qs[112 * 32];     // aliased as Os after compute
  __shared__ __align__(16) u16 Ks[128 * 32];
  __shared__ __align__(16) u16 Vt[32 * 136];
  __shared__ __align__(16) u16 Ps[4][16 * 136];  // per-wave slot
  const int b = blockIdx.x, h = blockIdx.y;
  const int t = threadIdx.x, w = t >> 6, ln = t & 63;
  const u16* qbase = qkv + (long)b * 98 * 1536 + h * 32;
  // stage Q (7 chunks of 16 rows) and K (8 chunks) via async global->LDS, 16B/lane
  {
    const int gr = ln >> 2, gc = (ln & 3) * 8;
    for (int n = w; n < 7; n += 4) {
      int g = n * 16 + gr; if (g > 97) g = 97;   // clamp: pad rows = row-97 copies
      __builtin_amdgcn_global_load_lds((as1_cvp)(const void*)(qbase + (long)g * 1536 + gc),
                                       (as3_vp)(Qs + n * 512), 16, 0, 0);
    }
    for (int n = w; n < 8; n += 4) {
      int g = n * 16 + gr; if (g > 97) g = 97;   // pad cols masked by baked -1e30 bias
      __builtin_amdgcn_global_load_lds((as1_cvp)(const void*)(qbase + 512 + (long)g * 1536 + gc),
                                       (as3_vp)(Ks + n * 512), 16, 0, 0);
    }
  }
  // zero only Vt pad cols 98..135 (j>=98 has P==0, but 0*NaN would poison)
  for (int z = t; z < 32 * 19; z += 256) {
    int d = z / 19, q = z % 19;
    *(unsigned int*)&Vt[d * 136 + 98 + q * 2] = 0u;
  }
  // stage V transposed
  for (int idx = t; idx < 784; idx += 256) {
    int i = idx >> 3, c4 = (idx & 7) * 4;
    ushort4 v4 = *(const ushort4*)(qbase + 1024 + (long)i * 1536 + c4);
    Vt[(c4 + 0) * 136 + i] = v4.x;
    Vt[(c4 + 1) * 136 + i] = v4.y;
    Vt[(c4 + 2) * 136 + i] = v4.z;
    Vt[(c4 + 3) * 136 + i] = v4.w;
  }
  __syncthreads();
  const int col = ln & 15, qrow = ln >> 4;
  const float scale = 0.17677669529663687f;  // 32^-0.5
  u16* Psw = &Ps[w][0];
  f32x4 o[2][2] = {{{0.f,0.f,0.f,0.f},{0.f,0.f,0.f,0.f}},{{0.f,0.f,0.f,0.f},{0.f,0.f,0.f,0.f}}};
  for (int tt = 0; tt < 2; ++tt) {
    const int ti = w + tt * 4;
    if (ti >= 7) break;
    // coalesced bias fragment loads: 8B per lane per j-tile
    const u16* bp = biasFrag + ((long)((h * 7 + ti) * 8) * 64 + ln) * 4;
    ushort4 bfv[8];
#pragma unroll
    for (int tj = 0; tj < 8; ++tj) bfv[tj] = *(const ushort4*)(bp + tj * 256);
    bf16x8 aq = *(const bf16x8*)&Qs[(ti * 16 + col) * 32 + qrow * 8];
    f32x4 s[8];
#pragma unroll
    for (int tj = 0; tj < 8; ++tj) {
      bf16x8 bk = *(const bf16x8*)&Ks[(tj * 16 + col) * 32 + qrow * 8];
      f32x4 z = {0.f, 0.f, 0.f, 0.f};
      s[tj] = __builtin_amdgcn_mfma_f32_16x16x32_bf16(aq, bk, z, 0, 0, 0);
    }
#pragma unroll
    for (int r = 0; r < 4; ++r) {
      float vals[8]; float m = -1e30f;
#pragma unroll
      for (int tj = 0; tj < 8; ++tj) {
        u16 bb = (r == 0) ? bfv[tj].x : (r == 1) ? bfv[tj].y : (r == 2) ? bfv[tj].z : bfv[tj].w;
        float v = fmaf(s[tj][r], scale, b2f(bb));
        vals[tj] = v; m = fmaxf(m, v);
      }
#pragma unroll
      for (int off = 1; off < 16; off <<= 1) m = fmaxf(m, __shfl_xor(m, off));
      float sum = 0.f;
#pragma unroll
      for (int tj = 0; tj < 8; ++tj) { vals[tj] = __expf(vals[tj] - m); sum += vals[tj]; }
#pragma unroll
      for (int off = 1; off < 16; off <<= 1) sum += __shfl_xor(sum, off);
      float inv = 1.f / sum;
      const int rt = qrow * 4 + r;
#pragma unroll
      for (int tj = 0; tj < 8; ++tj)
        Psw[rt * 136 + tj * 16 + col] = f2b(vals[tj] * inv);
    }
#pragma unroll
    for (int ks = 0; ks < 4; ++ks) {
      bf16x8 ap  = *(const bf16x8*)&Psw[col * 136 + ks * 32 + qrow * 8];
      bf16x8 bv0 = *(const bf16x8*)&Vt[col * 136 + ks * 32 + qrow * 8];
      bf16x8 bv1 = *(const bf16x8*)&Vt[(16 + col) * 136 + ks * 32 + qrow * 8];
      o[tt][0] = __builtin_amdgcn_mfma_f32_16x16x32_bf16(ap, bv0, o[tt][0], 0, 0, 0);
      o[tt][1] = __builtin_amdgcn_mfma_f32_16x16x32_bf16(ap, bv1, o[tt][1], 0, 0, 0);
    }
  }
  __syncthreads();   // everyone done reading Qs -> reuse as output staging
  u16* Os = Qs;
#pragma unroll
  for (int tt = 0; tt < 2; ++tt) {
    const int ti = w + tt * 4;
    if (ti >= 7) continue;
#pragma unroll
    for (int r = 0; r < 4; ++r) {
      const int i = ti * 16 + qrow * 4 + r;
      if (i < 98) {
        Os[i * 32 + col]      = f2b(o[tt][0][r]);
        Os[i * 32 + 16 + col] = f2b(o[tt][1][r]);
      }
    }
  }
  __syncthreads();
  u16* obase = attnout + (long)b * 98 * 512 + h * 32;
  for (int idx = t; idx < 784; idx += 256) {
    int i = idx >> 3, c4 = (idx & 7) * 4;
    *(ushort4*)(obase + (long)i * 512 + c4) = *(const ushort4*)&Os[i * 32 + c4];
  }
}

extern "C" void kernel_launch(void* const* d_in, const int* in_sizes, int n_in,
                              void* d_out, int out_size, void* d_ws, size_t ws_size,
                              hipStream_t stream) {
  (void)in_sizes; (void)n_in; (void)out_size; (void)ws_size;
  char* p = (char*)d_ws;
  u16* qkvbuf   = (u16*)p;  p += 50176L * 1536 * 2;   // 154,140,672
  u16* attnbuf  = (u16*)p;  u16* xb = attnbuf; p += 50176L * 512 * 2;  // 51,380,224
  u16* wqkvT    = (u16*)p;  p += 1536L * 512 * 2;     // 1,572,864
  u16* wprojT   = (u16*)p;  p += 512L * 512 * 2;      // 524,288
  u16* biasFrag = (u16*)p;  p += 57344L * 4 * 2;      // 458,752
  int* flagp    = (int*)p;

  k_detect<<<1, 64, 0, stream>>>((const u16*)d_in[0], flagp);
  k_convert<<<25088, 256, 0, stream>>>(d_in[0], xb, flagp);
  k_transpose<<<dim3(48, 16), dim3(32, 8), 0, stream>>>(d_in[1], wqkvT, flagp, 512, 1536);
  k_transpose<<<dim3(16, 16), dim3(32, 8), 0, stream>>>(d_in[3], wprojT, flagp, 512, 512);
  k_biasfrag<<<224, 256, 0, stream>>>((const int*)d_in[6], d_in[5], biasFrag, flagp);
  // qkv = x @ qkv_w + qkv_b   [50176 x 1536]
  k_gemm_bt<<<dim3(392, 12), 256, 0, stream>>>((const u16*)d_in[0], xb, wqkvT, d_in[2],
                                               qkvbuf, flagp, 1536, 512, 0);
  // attention -> attnbuf [50176 x 512]
  k_attn<<<dim3(512, 16), 256, 0, stream>>>(qkvbuf, biasFrag, attnbuf);
  // out = attnbuf @ proj_w + proj_b
  k_gemm_bt<<<dim3(392, 4), 256, 0, stream>>>(attnbuf, attnbuf, wprojT, d_in[4],
                                              d_out, flagp, 512, 512, 1);
}